// Round 6
// baseline (101.920 us; speedup 1.0000x reference)
//
#include <hip/hip_runtime.h>

// CompressK: ragged strided chunk gather + mean-pool.
//   k:          [total_tokens, H=4, D=128] f32   (row = 512 floats = 128 float4)
//   cu_seqlens: [B+1] int32
//   kernel_size (ks), kernel_stride (kst): scalar int32, device 1-elem arrays
// out = concat( compressed_k [N, H, D] f32 flat, cu_seqlens_compressed [B+1] as f32 )
//
// Fast path (ks % kst == 0, true for the bench: 32/16): window decomposition.
//   Phase 1: disjoint kst-row window sums -> d_ws. Perfectly linear stream of k,
//            every input byte read exactly once, no LDS, no sync.
//   Phase 2: chunk c = sum of r = ks/kst consecutive window sums (12.6 MB traffic).
// Fallback (ks % kst != 0, decided on-device): phase 2 does direct pooling.

#define HD4 128   // (H*D)/4 float4 columns per token row

__device__ __forceinline__ int chunks_of(int len, int ks, int kst) {
    return (len >= ks) ? ((len - ks) / kst + 1) : 0;
}

// Phase 1: window w covers rows [cu[b] + j*kst, +kst). Windows are disjoint.
__global__ __launch_bounds__(256)
void window_sum_kernel(const float* __restrict__ k,
                       const int* __restrict__ cu,
                       const int* __restrict__ ks_p,
                       const int* __restrict__ kst_p,
                       float4* __restrict__ wsum, int B) {
    const int ks = ks_p[0], kst = kst_p[0];
    if (kst <= 0 || ks <= 0 || (ks % kst) != 0) return;   // fallback handled in phase 2
    const int r = ks / kst;

    int total_w = 0;
    for (int b = 0; b < B; ++b) {
        int nc = chunks_of(cu[b + 1] - cu[b], ks, kst);
        total_w += nc ? nc + r - 1 : 0;
    }

    const int col = threadIdx.x & (HD4 - 1);
    const int sub = threadIdx.x >> 7;           // 2 windows per 256-thread block

    for (int w = blockIdx.x * 2 + sub; w < total_w; w += gridDim.x * 2) {
        int b = 0, pre = 0;
        for (;;) {
            int nc = chunks_of(cu[b + 1] - cu[b], ks, kst);
            int nw = nc ? nc + r - 1 : 0;
            if (w < pre + nw) break;
            pre += nw; ++b;
        }
        const int j = w - pre;
        const float4* __restrict__ src =
            (const float4*)k + (size_t)(cu[b] + j * kst) * HD4 + col;
        float4 acc = make_float4(0.f, 0.f, 0.f, 0.f);
        #pragma unroll 4
        for (int t = 0; t < kst; ++t) {
            float4 v = src[(size_t)t * HD4];
            acc.x += v.x; acc.y += v.y; acc.z += v.z; acc.w += v.w;
        }
        wsum[(size_t)w * HD4 + col] = acc;
    }
}

// Phase 2: combine window sums into chunk means (or direct pool on fallback).
__global__ __launch_bounds__(256)
void combine_kernel(const float* __restrict__ k,
                    const int* __restrict__ cu,
                    const int* __restrict__ ks_p,
                    const int* __restrict__ kst_p,
                    const float4* __restrict__ wsum,
                    float* __restrict__ out, int B, int out_size) {
    const int ks = ks_p[0], kst = kst_p[0];
    const float inv = 1.0f / (float)ks;
    const bool fast = (kst > 0) && (ks > 0) && ((ks % kst) == 0);
    const int r = fast ? ks / kst : 0;

    int total = 0;
    for (int b = 0; b < B; ++b) total += chunks_of(cu[b + 1] - cu[b], ks, kst);

    const int tid = threadIdx.x;
    if (blockIdx.x == 0 && tid <= B) {          // cu_seqlens_compressed tail (f32)
        int acc = 0;
        for (int b = 0; b < tid; ++b) acc += chunks_of(cu[b + 1] - cu[b], ks, kst);
        out[(size_t)out_size - (B + 1) + tid] = (float)acc;
    }

    const int col = tid & (HD4 - 1);
    const int sub = tid >> 7;                   // 2 chunks per 256-thread block

    for (int c = blockIdx.x * 2 + sub; c < total; c += gridDim.x * 2) {
        int b = 0, pre = 0, prew = 0;
        for (;;) {
            int nc = chunks_of(cu[b + 1] - cu[b], ks, kst);
            if (c < pre + nc) break;
            pre += nc; prew += nc ? nc + r - 1 : 0; ++b;
        }
        const int lc = c - pre;

        float4 acc = make_float4(0.f, 0.f, 0.f, 0.f);
        if (fast) {
            const float4* __restrict__ wp = wsum + (size_t)(prew + lc) * HD4 + col;
            #pragma unroll 2
            for (int t = 0; t < r; ++t) {
                float4 v = wp[(size_t)t * HD4];
                acc.x += v.x; acc.y += v.y; acc.z += v.z; acc.w += v.w;
            }
        } else {
            const float4* __restrict__ src =
                (const float4*)k + (size_t)(cu[b] + lc * kst) * HD4 + col;
            for (int t = 0; t < ks; ++t) {
                float4 v = src[(size_t)t * HD4];
                acc.x += v.x; acc.y += v.y; acc.z += v.z; acc.w += v.w;
            }
        }
        acc.x *= inv; acc.y *= inv; acc.z *= inv; acc.w *= inv;
        ((float4*)out)[(size_t)c * HD4 + col] = acc;
    }
}

extern "C" void kernel_launch(void* const* d_in, const int* in_sizes, int n_in,
                              void* d_out, int out_size, void* d_ws, size_t ws_size,
                              hipStream_t stream) {
    const float* k    = (const float*)d_in[0];
    const int*   cu   = (const int*)d_in[1];
    const int*   ksp  = (const int*)d_in[2];
    const int*   kstp = (const int*)d_in[3];
    float*  out  = (float*)d_out;
    float4* wsum = (float4*)d_ws;

    const int B = in_sizes[1] - 1;

    // Phase 1: ~2048 windows for the bench shape; 1024 blocks x 2 windows,
    // grid-stride covers larger counts. Linear streaming of k.
    window_sum_kernel<<<1024, 256, 0, stream>>>(k, cu, ksp, kstp, wsum, B);
    // Phase 2: ~2044 chunks; 1024 blocks x 2 chunks, grid-stride beyond.
    combine_kernel<<<1024, 256, 0, stream>>>(k, cu, ksp, kstp, wsum, out, B, out_size);
}